// Round 1
// baseline (3670.325 us; speedup 1.0000x reference)
//
#include <hip/hip_runtime.h>
#include <hip/hip_bf16.h>
#include <math.h>

// SBERTa forward, MI355X gfx950.
// B=8 T=512 D=768 L=12 H=12 F=3072 K=2 DH=64, N_tok=4096.
// All GEMMs: bf16 MFMA 16x16x32, NT layout (both operands K-contiguous),
// 128x128x32 block tile, 4 waves, 4x4 16x16 subtiles per wave (m93 structure).

typedef __bf16 bf16;
typedef __attribute__((ext_vector_type(8))) __bf16 bf16x8;
typedef __attribute__((ext_vector_type(4))) __bf16 bf16x4;
typedef __attribute__((ext_vector_type(4))) float f32x4;

#define N_TOK 4096
#define D_SZ 768
#define F_SZ 3072
#define H_SZ 12
#define T_SZ 512
#define L_SZ 12

// ---------------------------------------------------------------- reductions
__device__ inline void block_reduce2(float& a, float& b, int tid) {
  #pragma unroll
  for (int off = 32; off; off >>= 1) {
    a += __shfl_xor(a, off);
    b += __shfl_xor(b, off);
  }
  __shared__ float red[8];
  if ((tid & 63) == 0) { red[tid >> 6] = a; red[4 + (tid >> 6)] = b; }
  __syncthreads();
  a = red[0] + red[1] + red[2] + red[3];
  b = red[4] + red[5] + red[6] + red[7];
  __syncthreads();
}

// ---------------------------------------------------------------- converts
__global__ void __launch_bounds__(256) f2b_kernel(const float* __restrict__ src,
                                                  bf16* __restrict__ dst, int n4) {
  int i = blockIdx.x * 256 + threadIdx.x;
  if (i >= n4) return;
  float4 v = ((const float4*)src)[i];
  bf16x4 o; o.x = (bf16)v.x; o.y = (bf16)v.y; o.z = (bf16)v.z; o.w = (bf16)v.w;
  *(bf16x4*)(dst + (size_t)i * 4) = o;
}

// wqkv layout: per layer, rows 0..767 = Wq[l], 768..1535 = Wk[l], 1536.. = Wv[l]; ld=768
__global__ void __launch_bounds__(256) build_wqkv_kernel(const float* __restrict__ Wq,
    const float* __restrict__ Wk, const float* __restrict__ Wv, bf16* __restrict__ dst) {
  int i = blockIdx.x * 256 + threadIdx.x;
  const int per_layer = 2304 * 768;
  long idx = (long)i * 4;
  if (idx >= 12L * per_layer) return;
  int l = (int)(idx / per_layer);
  int rem = (int)(idx - (long)l * per_layer);
  int r = rem / 768;
  int c = rem - r * 768;
  const float* src;
  if (r < 768)       src = Wq + ((size_t)l * 768 + r) * 768 + c;
  else if (r < 1536) src = Wk + ((size_t)l * 768 + (r - 768)) * 768 + c;
  else               src = Wv + ((size_t)l * 768 + (r - 1536)) * 768 + c;
  float4 v = *(const float4*)src;
  bf16x4 o; o.x = (bf16)v.x; o.y = (bf16)v.y; o.z = (bf16)v.z; o.w = (bf16)v.w;
  *(bf16x4*)(dst + idx) = o;
}

// v (in qkv cols 1536..2303, per-head) -> vt[b,h,dh,t] so PV B-frags are 16B contiguous
__global__ void __launch_bounds__(256) build_vt_kernel(const bf16* __restrict__ qkv,
                                                       bf16* __restrict__ vt) {
  int o = blockIdx.x * 256 + threadIdx.x;  // < 8*12*64*512 = 3145728
  int t  = o & 511;
  int r  = o >> 9;
  int dh = r & 63;
  int bh = r >> 6;
  int h = bh % 12, b = bh / 12;
  vt[o] = qkv[(size_t)(b * 512 + t) * 2304 + 1536 + h * 64 + dh];
}

// ---------------------------------------------------------------- embedding
// h_base = tok_emb[id] + pos_emb[t]; p = softmax(h_base . proto^T / tau)
__global__ void __launch_bounds__(256) embed_a_kernel(const int* __restrict__ ids,
    const float* __restrict__ tok, const float* __restrict__ pos,
    const float* __restrict__ proto, const float* __restrict__ log_tau,
    float* __restrict__ h_base, float* __restrict__ p_out) {
  int n = blockIdx.x;
  int t = n & 511;
  int tid = threadIdx.x;
  int id = ids[n];
  float d0 = 0.f, d1 = 0.f;
  #pragma unroll
  for (int jj = 0; jj < 3; jj++) {
    int j = tid + jj * 256;
    float v = tok[(size_t)id * 768 + j] + pos[(size_t)t * 768 + j];
    h_base[(size_t)n * 768 + j] = v;
    d0 += v * proto[j];
    d1 += v * proto[768 + j];
  }
  block_reduce2(d0, d1, tid);
  if (tid == 0) {
    float tau = fmaxf(__expf(log_tau[0]), 0.25f);
    float a = d0 / tau, bb = d1 / tau;
    float m = fmaxf(a, bb);
    float e0 = __expf(a - m), e1 = __expf(bb - m);
    float si = e0 + e1;
    p_out[n * 2] = e0 / si;
    p_out[n * 2 + 1] = e1 / si;
  }
}

// s[t] = t==0 ? 0 : 1 - p[t].p[t-1]; h = LN(h_base + p@lang + s*switch)
__global__ void __launch_bounds__(256) embed_c_kernel(const float* __restrict__ h_base,
    const float* __restrict__ p, const float* __restrict__ lang, const float* __restrict__ sw,
    const float* __restrict__ lw, const float* __restrict__ lb,
    float* __restrict__ s_out, float* __restrict__ h_out, bf16* __restrict__ h_bf) {
  int n = blockIdx.x;
  int t = n & 511;
  int tid = threadIdx.x;
  float p0 = p[n * 2], p1 = p[n * 2 + 1];
  float sv = 0.f;
  if (t > 0) sv = 1.f - (p0 * p[(n - 1) * 2] + p1 * p[(n - 1) * 2 + 1]);
  if (tid == 0) s_out[n] = sv;
  float x[3]; float sum = 0.f, sq = 0.f;
  #pragma unroll
  for (int jj = 0; jj < 3; jj++) {
    int j = tid + jj * 256;
    float v = h_base[(size_t)n * 768 + j] + p0 * lang[j] + p1 * lang[768 + j] + sv * sw[j];
    x[jj] = v; sum += v; sq += v * v;
  }
  block_reduce2(sum, sq, tid);
  float mean = sum * (1.f / 768.f);
  float var = fmaxf(sq * (1.f / 768.f) - mean * mean, 0.f);
  float inv = rsqrtf(var + 1e-12f);
  #pragma unroll
  for (int jj = 0; jj < 3; jj++) {
    int j = tid + jj * 256;
    float o = (x[jj] - mean) * inv * lw[j] + lb[j];
    h_out[(size_t)n * 768 + j] = o;
    h_bf[(size_t)n * 768 + j] = (bf16)o;
  }
}

// ---------------------------------------------------------------- fused LN
// out = LN(x1 + x2 + bias) * w + bv ; writes fp32 + bf16
__global__ void __launch_bounds__(256) ln_kernel(const float* __restrict__ x1,
    const float* __restrict__ x2, const float* __restrict__ bias,
    const float* __restrict__ w, const float* __restrict__ bv,
    float* __restrict__ out_f, bf16* __restrict__ out_b) {
  int n = blockIdx.x;
  int tid = threadIdx.x;
  float x[3]; float sum = 0.f, sq = 0.f;
  #pragma unroll
  for (int jj = 0; jj < 3; jj++) {
    int j = tid + jj * 256;
    float v = x1[(size_t)n * 768 + j] + x2[(size_t)n * 768 + j] + bias[j];
    x[jj] = v; sum += v; sq += v * v;
  }
  block_reduce2(sum, sq, tid);
  float mean = sum * (1.f / 768.f);
  float var = fmaxf(sq * (1.f / 768.f) - mean * mean, 0.f);
  float inv = rsqrtf(var + 1e-12f);
  #pragma unroll
  for (int jj = 0; jj < 3; jj++) {
    int j = tid + jj * 256;
    float o = (x[jj] - mean) * inv * w[j] + bv[j];
    out_f[(size_t)n * 768 + j] = o;
    out_b[(size_t)n * 768 + j] = (bf16)o;
  }
}

// ---------------------------------------------------------------- GEMM (NT)
// C[m,n] = sum_k A[m,k]*B[n,k]. MODE 0: bf16 out. 1: f32 out. 2: bias+gelu, bf16 out.
template <int MODE>
__global__ void __launch_bounds__(256) gemm_nt(const bf16* __restrict__ A,
    const bf16* __restrict__ B, void* __restrict__ C, const float* __restrict__ bias,
    int M, int N, int K) {
  __shared__ bf16 As[128 * 32];
  __shared__ bf16 Bs[128 * 32];
  const int tid = threadIdx.x;
  const int lane = tid & 63;
  const int wave = tid >> 6;
  const int wm = wave >> 1, wn = wave & 1;
  const int m0 = blockIdx.x * 128, n0 = blockIdx.y * 128;
  const int fr = lane & 15, fq = lane >> 4;
  const int sr = tid >> 2;        // staging row 0..63
  const int scf = (tid & 3) * 8;  // staging col 0,8,16,24

  f32x4 acc[4][4] = {};
  const bf16* Aptr = A + (size_t)(m0 + sr) * K + scf;
  const bf16* Bptr = B + (size_t)(n0 + sr) * K + scf;
  for (int k0 = 0; k0 < K; k0 += 32) {
    #pragma unroll
    for (int it = 0; it < 2; ++it) {
      *(bf16x8*)&As[(sr + it * 64) * 32 + scf] = *(const bf16x8*)(Aptr + (size_t)it * 64 * K + k0);
      *(bf16x8*)&Bs[(sr + it * 64) * 32 + scf] = *(const bf16x8*)(Bptr + (size_t)it * 64 * K + k0);
    }
    __syncthreads();
    bf16x8 af[4], bfr[4];
    #pragma unroll
    for (int i = 0; i < 4; i++) af[i]  = *(const bf16x8*)&As[(wm * 64 + i * 16 + fr) * 32 + fq * 8];
    #pragma unroll
    for (int i = 0; i < 4; i++) bfr[i] = *(const bf16x8*)&Bs[(wn * 64 + i * 16 + fr) * 32 + fq * 8];
    #pragma unroll
    for (int i = 0; i < 4; i++)
      #pragma unroll
      for (int j = 0; j < 4; j++)
        acc[i][j] = __builtin_amdgcn_mfma_f32_16x16x32_bf16(af[i], bfr[j], acc[i][j], 0, 0, 0);
    __syncthreads();
  }
  #pragma unroll
  for (int i = 0; i < 4; i++) {
    int row0 = m0 + wm * 64 + i * 16 + fq * 4;
    #pragma unroll
    for (int j = 0; j < 4; j++) {
      int col = n0 + wn * 64 + j * 16 + fr;
      #pragma unroll
      for (int r = 0; r < 4; r++) {
        float v = acc[i][j][r];
        size_t off = (size_t)(row0 + r) * N + col;
        if (MODE == 2) {
          v += bias[col];
          v = 0.5f * v * (1.f + erff(v * 0.70710678118654752f));
        }
        if (MODE == 1) ((float*)C)[off] = v;
        else           ((bf16*)C)[off] = (bf16)v;
      }
    }
  }
}

// ---------------------------------------------------------------- attention
// One block = (b, h, 32 q-rows). Phase1: S = Q K^T * scale (MFMA -> LDS fp32).
// Phase2: softmax rows with bias cp_i.p_j + gamma*s_j + mask. Phase3: ctx = P V (MFMA).
__global__ void __launch_bounds__(256) attn_kernel(const bf16* __restrict__ qkv,
    const bf16* __restrict__ vt, const float* __restrict__ p, const float* __restrict__ s,
    const int* __restrict__ mask, const float* __restrict__ compat,
    const float* __restrict__ gamma, int l, bf16* __restrict__ ctx) {
  __shared__ float scb[32 * 512];  // 64 KB
  const int tid = threadIdx.x;
  const int lane = tid & 63;
  const int w = tid >> 6;
  const int fr = lane & 15, fq = lane >> 4;
  const int qc = blockIdx.x, h = blockIdx.y, b = blockIdx.z;
  const int i0 = qc * 32;
  const float* Cm = compat + (size_t)(l * 12 + h) * 4;  // 2x2 row-major [k][j]
  const float gl = gamma[l];

  // ---- phase 1: scores
  bf16x8 qf[2][2];
  #pragma unroll
  for (int mt = 0; mt < 2; mt++)
    #pragma unroll
    for (int kk = 0; kk < 2; kk++)
      qf[mt][kk] = *(const bf16x8*)&qkv[(size_t)(b * 512 + i0 + mt * 16 + fr) * 2304 + h * 64 + kk * 32 + fq * 8];
  for (int ntl = 0; ntl < 8; ++ntl) {
    int j0 = (w * 8 + ntl) * 16;
    bf16x8 kf0 = *(const bf16x8*)&qkv[(size_t)(b * 512 + j0 + fr) * 2304 + 768 + h * 64 + fq * 8];
    bf16x8 kf1 = *(const bf16x8*)&qkv[(size_t)(b * 512 + j0 + fr) * 2304 + 768 + h * 64 + 32 + fq * 8];
    #pragma unroll
    for (int mt = 0; mt < 2; mt++) {
      f32x4 acc = {};
      acc = __builtin_amdgcn_mfma_f32_16x16x32_bf16(qf[mt][0], kf0, acc, 0, 0, 0);
      acc = __builtin_amdgcn_mfma_f32_16x16x32_bf16(qf[mt][1], kf1, acc, 0, 0, 0);
      #pragma unroll
      for (int r = 0; r < 4; r++)
        scb[(mt * 16 + fq * 4 + r) * 512 + j0 + fr] = acc[r] * 0.125f;
    }
  }
  __syncthreads();

  // ---- phase 2: bias + softmax (8 rows per wave, 8 cols per lane, stride 64)
  for (int il = 0; il < 8; ++il) {
    int i = w * 8 + il;
    int qi = i0 + i;
    float p0 = p[(b * 512 + qi) * 2], p1 = p[(b * 512 + qi) * 2 + 1];
    float cp0 = p0 * Cm[0] + p1 * Cm[2];
    float cp1 = p0 * Cm[1] + p1 * Cm[3];
    float x[8]; float mx = -3.0e38f;
    #pragma unroll
    for (int jj = 0; jj < 8; jj++) {
      int j = lane + jj * 64;
      float pj0 = p[(b * 512 + j) * 2], pj1 = p[(b * 512 + j) * 2 + 1];
      float add = (1.f - (float)mask[b * 512 + j]) * -10000.f;
      float v = scb[i * 512 + j] + cp0 * pj0 + cp1 * pj1 + gl * s[b * 512 + j] + add;
      x[jj] = v; mx = fmaxf(mx, v);
    }
    #pragma unroll
    for (int off = 32; off; off >>= 1) mx = fmaxf(mx, __shfl_xor(mx, off));
    float sum = 0.f;
    #pragma unroll
    for (int jj = 0; jj < 8; jj++) { float e = __expf(x[jj] - mx); x[jj] = e; sum += e; }
    #pragma unroll
    for (int off = 32; off; off >>= 1) sum += __shfl_xor(sum, off);
    float inv = 1.f / sum;
    #pragma unroll
    for (int jj = 0; jj < 8; jj++) scb[i * 512 + lane + jj * 64] = x[jj] * inv;
  }
  __syncthreads();

  // ---- phase 3: ctx = P V. wave -> (mt = w&1, two dh-tiles)
  const int mt = w & 1;
  const int ntb = (w >> 1) * 2;
  f32x4 acc[2] = {};
  for (int kt = 0; kt < 16; ++kt) {
    bf16x8 af;
    const float* prow = &scb[(mt * 16 + fr) * 512 + kt * 32 + fq * 8];
    #pragma unroll
    for (int jj = 0; jj < 8; jj++) af[jj] = (bf16)prow[jj];
    #pragma unroll
    for (int np = 0; np < 2; np++) {
      bf16x8 vf = *(const bf16x8*)&vt[(size_t)((b * 12 + h) * 64 + (ntb + np) * 16 + fr) * 512 + kt * 32 + fq * 8];
      acc[np] = __builtin_amdgcn_mfma_f32_16x16x32_bf16(af, vf, acc[np], 0, 0, 0);
    }
  }
  #pragma unroll
  for (int np = 0; np < 2; np++)
    #pragma unroll
    for (int r = 0; r < 4; r++)
      ctx[(size_t)(b * 512 + i0 + mt * 16 + fq * 4 + r) * 768 + h * 64 + (ntb + np) * 16 + fr] = (bf16)acc[np][r];
}

// ---------------------------------------------------------------- launcher
extern "C" void kernel_launch(void* const* d_in, const int* in_sizes, int n_in,
                              void* d_out, int out_size, void* d_ws, size_t ws_size,
                              hipStream_t stream) {
  const int*   input_ids  = (const int*)d_in[0];
  const int*   attn_mask  = (const int*)d_in[1];
  const float* tok_emb    = (const float*)d_in[2];
  const float* pos_emb    = (const float*)d_in[3];
  const float* lang_emb   = (const float*)d_in[4];
  const float* switch_emb = (const float*)d_in[5];
  const float* prototypes = (const float*)d_in[6];
  const float* log_tau    = (const float*)d_in[7];
  const float* emb_ln_w   = (const float*)d_in[8];
  const float* emb_ln_b   = (const float*)d_in[9];
  const float* Wq   = (const float*)d_in[10];
  const float* Wk   = (const float*)d_in[11];
  const float* Wv   = (const float*)d_in[12];
  const float* Wo   = (const float*)d_in[13];
  const float* Wo_b = (const float*)d_in[14];
  const float* compat = (const float*)d_in[15];
  const float* gamma  = (const float*)d_in[16];
  const float* W1   = (const float*)d_in[17];
  const float* b1   = (const float*)d_in[18];
  const float* W2   = (const float*)d_in[19];
  const float* b2   = (const float*)d_in[20];
  const float* ln1_w = (const float*)d_in[21];
  const float* ln1_b = (const float*)d_in[22];
  const float* ln2_w = (const float*)d_in[23];
  const float* ln2_b = (const float*)d_in[24];

  char* wsp = (char*)d_ws;
  size_t off = 0;
  auto alloc = [&](size_t bytes) { void* pp = wsp + off; off += (bytes + 255) & ~(size_t)255; return pp; };
  float* h_f      = (float*)alloc((size_t)N_TOK * D_SZ * 4);
  bf16*  h_bf     = (bf16*)alloc((size_t)N_TOK * D_SZ * 2);
  float* h_base   = (float*)alloc((size_t)N_TOK * D_SZ * 4);
  float* h_mid    = (float*)alloc((size_t)N_TOK * D_SZ * 4);
  bf16*  h_mid_bf = (bf16*)alloc((size_t)N_TOK * D_SZ * 2);
  float* tmp      = (float*)alloc((size_t)N_TOK * D_SZ * 4);
  float* p_buf    = (float*)alloc((size_t)N_TOK * 2 * 4);
  float* s_buf    = (float*)alloc((size_t)N_TOK * 4);
  bf16*  qkv      = (bf16*)alloc((size_t)N_TOK * 2304 * 2);
  bf16*  vt       = (bf16*)alloc((size_t)N_TOK * D_SZ * 2);
  bf16*  ctx      = (bf16*)alloc((size_t)N_TOK * D_SZ * 2);
  bf16*  a1       = (bf16*)alloc((size_t)N_TOK * F_SZ * 2);
  bf16*  wqkv_bf  = (bf16*)alloc((size_t)L_SZ * 2304 * 768 * 2);
  bf16*  wo_bf    = (bf16*)alloc((size_t)L_SZ * 768 * 768 * 2);
  bf16*  w1_bf    = (bf16*)alloc((size_t)L_SZ * 3072 * 768 * 2);
  bf16*  w2_bf    = (bf16*)alloc((size_t)L_SZ * 768 * 3072 * 2);
  (void)ws_size; (void)in_sizes; (void)n_in; (void)out_size;

  // weight conversion (every call; inputs are restored each timed iteration)
  build_wqkv_kernel<<<(12 * 2304 * 768 / 4 + 255) / 256, 256, 0, stream>>>(Wq, Wk, Wv, wqkv_bf);
  f2b_kernel<<<(12 * 768 * 768 / 4 + 255) / 256, 256, 0, stream>>>(Wo, wo_bf, 12 * 768 * 768 / 4);
  f2b_kernel<<<(12 * 3072 * 768 / 4 + 255) / 256, 256, 0, stream>>>(W1, w1_bf, 12 * 3072 * 768 / 4);
  f2b_kernel<<<(12 * 768 * 3072 / 4 + 255) / 256, 256, 0, stream>>>(W2, w2_bf, 12 * 768 * 3072 / 4);

  // embedding stage
  embed_a_kernel<<<N_TOK, 256, 0, stream>>>(input_ids, tok_emb, pos_emb, prototypes, log_tau,
                                            h_base, p_buf);
  embed_c_kernel<<<N_TOK, 256, 0, stream>>>(h_base, p_buf, lang_emb, switch_emb, emb_ln_w,
                                            emb_ln_b, s_buf, h_f, h_bf);

  for (int l = 0; l < 12; ++l) {
    gemm_nt<0><<<dim3(32, 18), 256, 0, stream>>>(h_bf, wqkv_bf + (size_t)l * 2304 * 768, qkv,
                                                 nullptr, N_TOK, 2304, 768);
    build_vt_kernel<<<N_TOK * D_SZ / 256, 256, 0, stream>>>(qkv, vt);
    attn_kernel<<<dim3(16, 12, 8), 256, 0, stream>>>(qkv, vt, p_buf, s_buf, attn_mask,
                                                     compat, gamma, l, ctx);
    gemm_nt<1><<<dim3(32, 6), 256, 0, stream>>>(ctx, wo_bf + (size_t)l * 768 * 768, tmp,
                                                nullptr, N_TOK, 768, 768);
    ln_kernel<<<N_TOK, 256, 0, stream>>>(h_f, tmp, Wo_b + l * 768, ln1_w + l * 768,
                                         ln1_b + l * 768, h_mid, h_mid_bf);
    gemm_nt<2><<<dim3(32, 24), 256, 0, stream>>>(h_mid_bf, w1_bf + (size_t)l * 3072 * 768, a1,
                                                 b1 + l * 3072, N_TOK, 3072, 768);
    gemm_nt<1><<<dim3(32, 6), 256, 0, stream>>>(a1, w2_bf + (size_t)l * 768 * 3072, tmp,
                                                nullptr, N_TOK, 768, 3072);
    float* hdst = (l == 11) ? (float*)d_out : h_f;
    ln_kernel<<<N_TOK, 256, 0, stream>>>(h_mid, tmp, b2 + l * 768, ln2_w + l * 768,
                                         ln2_b + l * 768, hdst, h_bf);
  }
}

// Round 2
// 3102.654 us; speedup vs baseline: 1.1830x; 1.1830x over previous
//
#include <hip/hip_runtime.h>
#include <hip/hip_bf16.h>
#include <math.h>

// SBERTa forward, MI355X gfx950.
// B=8 T=512 D=768 L=12 H=12 F=3072 K=2 DH=64, N_tok=4096.
// GEMMs: bf16 MFMA 16x16x32, NT layout, 128x128x32 tile, 4 waves (m97 structure:
// global_load_lds width-16 async staging). Wo/W2 use split-K=2 (grid starvation fix).
// V-transpose fused into QKV GEMM epilogue (MODE 3).

typedef __bf16 bf16;
typedef __attribute__((ext_vector_type(8))) __bf16 bf16x8;
typedef __attribute__((ext_vector_type(4))) __bf16 bf16x4;
typedef __attribute__((ext_vector_type(4))) float f32x4;

#define N_TOK 4096
#define D_SZ 768
#define F_SZ 3072
#define L_SZ 12
#define MN_SZ ((size_t)N_TOK * D_SZ)

// async global->LDS, 16B per lane, wave-uniform LDS base + lane*16
__device__ __forceinline__ void async_ld16(const void* g, void* l) {
  __builtin_amdgcn_global_load_lds((const __attribute__((address_space(1))) void*)g,
                                   (__attribute__((address_space(3))) void*)l, 16, 0, 0);
}

// ---------------------------------------------------------------- reductions
__device__ inline void block_reduce2(float& a, float& b, int tid) {
  #pragma unroll
  for (int off = 32; off; off >>= 1) {
    a += __shfl_xor(a, off);
    b += __shfl_xor(b, off);
  }
  __shared__ float red[8];
  if ((tid & 63) == 0) { red[tid >> 6] = a; red[4 + (tid >> 6)] = b; }
  __syncthreads();
  a = red[0] + red[1] + red[2] + red[3];
  b = red[4] + red[5] + red[6] + red[7];
  __syncthreads();
}

// ---------------------------------------------------------------- converts
__global__ void __launch_bounds__(256) f2b_kernel(const float* __restrict__ src,
                                                  bf16* __restrict__ dst, int n4) {
  int i = blockIdx.x * 256 + threadIdx.x;
  if (i >= n4) return;
  float4 v = ((const float4*)src)[i];
  bf16x4 o; o.x = (bf16)v.x; o.y = (bf16)v.y; o.z = (bf16)v.z; o.w = (bf16)v.w;
  *(bf16x4*)(dst + (size_t)i * 4) = o;
}

// wqkv layout: per layer, rows 0..767 = Wq[l], 768..1535 = Wk[l], 1536.. = Wv[l]; ld=768
__global__ void __launch_bounds__(256) build_wqkv_kernel(const float* __restrict__ Wq,
    const float* __restrict__ Wk, const float* __restrict__ Wv, bf16* __restrict__ dst) {
  int i = blockIdx.x * 256 + threadIdx.x;
  const int per_layer = 2304 * 768;
  long idx = (long)i * 4;
  if (idx >= 12L * per_layer) return;
  int l = (int)(idx / per_layer);
  int rem = (int)(idx - (long)l * per_layer);
  int r = rem / 768;
  int c = rem - r * 768;
  const float* src;
  if (r < 768)       src = Wq + ((size_t)l * 768 + r) * 768 + c;
  else if (r < 1536) src = Wk + ((size_t)l * 768 + (r - 768)) * 768 + c;
  else               src = Wv + ((size_t)l * 768 + (r - 1536)) * 768 + c;
  float4 v = *(const float4*)src;
  bf16x4 o; o.x = (bf16)v.x; o.y = (bf16)v.y; o.z = (bf16)v.z; o.w = (bf16)v.w;
  *(bf16x4*)(dst + idx) = o;
}

// ---------------------------------------------------------------- embedding
__global__ void __launch_bounds__(256) embed_a_kernel(const int* __restrict__ ids,
    const float* __restrict__ tok, const float* __restrict__ pos,
    const float* __restrict__ proto, const float* __restrict__ log_tau,
    float* __restrict__ h_base, float* __restrict__ p_out) {
  int n = blockIdx.x;
  int t = n & 511;
  int tid = threadIdx.x;
  int id = ids[n];
  float d0 = 0.f, d1 = 0.f;
  #pragma unroll
  for (int jj = 0; jj < 3; jj++) {
    int j = tid + jj * 256;
    float v = tok[(size_t)id * 768 + j] + pos[(size_t)t * 768 + j];
    h_base[(size_t)n * 768 + j] = v;
    d0 += v * proto[j];
    d1 += v * proto[768 + j];
  }
  block_reduce2(d0, d1, tid);
  if (tid == 0) {
    float tau = fmaxf(__expf(log_tau[0]), 0.25f);
    float a = d0 / tau, bb = d1 / tau;
    float m = fmaxf(a, bb);
    float e0 = __expf(a - m), e1 = __expf(bb - m);
    float si = e0 + e1;
    p_out[n * 2] = e0 / si;
    p_out[n * 2 + 1] = e1 / si;
  }
}

__global__ void __launch_bounds__(256) embed_c_kernel(const float* __restrict__ h_base,
    const float* __restrict__ p, const float* __restrict__ lang, const float* __restrict__ sw,
    const float* __restrict__ lw, const float* __restrict__ lb,
    float* __restrict__ s_out, float* __restrict__ h_out, bf16* __restrict__ h_bf) {
  int n = blockIdx.x;
  int t = n & 511;
  int tid = threadIdx.x;
  float p0 = p[n * 2], p1 = p[n * 2 + 1];
  float sv = 0.f;
  if (t > 0) sv = 1.f - (p0 * p[(n - 1) * 2] + p1 * p[(n - 1) * 2 + 1]);
  if (tid == 0) s_out[n] = sv;
  float x[3]; float sum = 0.f, sq = 0.f;
  #pragma unroll
  for (int jj = 0; jj < 3; jj++) {
    int j = tid + jj * 256;
    float v = h_base[(size_t)n * 768 + j] + p0 * lang[j] + p1 * lang[768 + j] + sv * sw[j];
    x[jj] = v; sum += v; sq += v * v;
  }
  block_reduce2(sum, sq, tid);
  float mean = sum * (1.f / 768.f);
  float var = fmaxf(sq * (1.f / 768.f) - mean * mean, 0.f);
  float inv = rsqrtf(var + 1e-12f);
  #pragma unroll
  for (int jj = 0; jj < 3; jj++) {
    int j = tid + jj * 256;
    float o = (x[jj] - mean) * inv * lw[j] + lb[j];
    h_out[(size_t)n * 768 + j] = o;
    h_bf[(size_t)n * 768 + j] = (bf16)o;
  }
}

// ---------------------------------------------------------------- fused LN (3 inputs)
// out = LN(x1 + x2 + x3 + bias) * w + bv ; writes fp32 + bf16
__global__ void __launch_bounds__(256) ln3_kernel(const float* __restrict__ x1,
    const float* __restrict__ x2, const float* __restrict__ x3, const float* __restrict__ bias,
    const float* __restrict__ w, const float* __restrict__ bv,
    float* __restrict__ out_f, bf16* __restrict__ out_b) {
  int n = blockIdx.x;
  int tid = threadIdx.x;
  float x[3]; float sum = 0.f, sq = 0.f;
  #pragma unroll
  for (int jj = 0; jj < 3; jj++) {
    int j = tid + jj * 256;
    size_t o = (size_t)n * 768 + j;
    float v = x1[o] + x2[o] + x3[o] + bias[j];
    x[jj] = v; sum += v; sq += v * v;
  }
  block_reduce2(sum, sq, tid);
  float mean = sum * (1.f / 768.f);
  float var = fmaxf(sq * (1.f / 768.f) - mean * mean, 0.f);
  float inv = rsqrtf(var + 1e-12f);
  #pragma unroll
  for (int jj = 0; jj < 3; jj++) {
    int j = tid + jj * 256;
    float o = (x[jj] - mean) * inv * w[j] + bv[j];
    out_f[(size_t)n * 768 + j] = o;
    out_b[(size_t)n * 768 + j] = (bf16)o;
  }
}

// ---------------------------------------------------------------- GEMM (NT)
// C[m,n] = sum_k A[m,k]*B[n,k].
// MODE 1: f32 out, split-K=2 over blockIdx.z, out C + z*M*N.
// MODE 2: bias+gelu, bf16 out.
// MODE 3: QKV: cols <1536 -> bf16 C (ld 1536); cols >=1536 -> transposed into vt C2.
template <int MODE>
__global__ void __launch_bounds__(256) gemm_nt(const bf16* __restrict__ A,
    const bf16* __restrict__ B, void* __restrict__ C, bf16* __restrict__ C2,
    const float* __restrict__ bias, int M, int N, int K) {
  __shared__ bf16 As[128 * 32];
  __shared__ bf16 Bs[128 * 32];
  const int tid = threadIdx.x;
  const int lane = tid & 63;
  const int wave = tid >> 6;
  const int wm = wave >> 1, wn = wave & 1;
  const int m0 = blockIdx.x * 128, n0 = blockIdx.y * 128;
  const int fr = lane & 15, fq = lane >> 4;
  // async staging: wave covers rows wave*16 + it*64; lane -> row lane>>2, col (lane&3)*8
  const int srow = wave * 16 + (lane >> 2);
  const int scol = (lane & 3) * 8;

  int kb = 0, ke = K;
  if (MODE == 1) { int half = K >> 1; kb = blockIdx.z * half; ke = kb + half; }

  f32x4 acc[4][4] = {};
  const bf16* Ap = A + (size_t)(m0 + srow) * K + scol;
  const bf16* Bp = B + (size_t)(n0 + srow) * K + scol;
  bf16* AsW = &As[wave * 512];
  bf16* BsW = &Bs[wave * 512];
  for (int k0 = kb; k0 < ke; k0 += 32) {
    async_ld16(Ap + k0, AsW);
    async_ld16(Ap + (size_t)64 * K + k0, AsW + 64 * 32);
    async_ld16(Bp + k0, BsW);
    async_ld16(Bp + (size_t)64 * K + k0, BsW + 64 * 32);
    __syncthreads();
    bf16x8 af[4], bfr[4];
    #pragma unroll
    for (int i = 0; i < 4; i++) af[i]  = *(const bf16x8*)&As[(wm * 64 + i * 16 + fr) * 32 + fq * 8];
    #pragma unroll
    for (int i = 0; i < 4; i++) bfr[i] = *(const bf16x8*)&Bs[(wn * 64 + i * 16 + fr) * 32 + fq * 8];
    #pragma unroll
    for (int i = 0; i < 4; i++)
      #pragma unroll
      for (int j = 0; j < 4; j++)
        acc[i][j] = __builtin_amdgcn_mfma_f32_16x16x32_bf16(af[i], bfr[j], acc[i][j], 0, 0, 0);
    __syncthreads();
  }

  const bool vregion = (MODE == 3) && (n0 >= 1536);
  float* Cz = (MODE == 1) ? ((float*)C + (size_t)blockIdx.z * M * N) : (float*)C;
  #pragma unroll
  for (int i = 0; i < 4; i++) {
    int row0 = m0 + wm * 64 + i * 16 + fq * 4;
    #pragma unroll
    for (int j = 0; j < 4; j++) {
      int col = n0 + wn * 64 + j * 16 + fr;
      if (MODE == 3 && vregion) {
        // V-transpose: quad rows = 4 consecutive t, col -> (h, dh)
        int vcol = col - 1536;
        int h = vcol >> 6, dh = vcol & 63;
        int b = row0 >> 9, t0 = row0 & 511;
        bf16x4 o;
        #pragma unroll
        for (int r = 0; r < 4; r++) o[r] = (bf16)acc[i][j][r];
        *(bf16x4*)&C2[((size_t)(b * 12 + h) * 64 + dh) * 512 + t0] = o;
      } else {
        #pragma unroll
        for (int r = 0; r < 4; r++) {
          float v = acc[i][j][r];
          if (MODE == 2) {
            v += bias[col];
            v = 0.5f * v * (1.f + erff(v * 0.70710678118654752f));
          }
          if (MODE == 1)      Cz[(size_t)(row0 + r) * N + col] = v;
          else if (MODE == 3) ((bf16*)C)[(size_t)(row0 + r) * 1536 + col] = (bf16)v;
          else                ((bf16*)C)[(size_t)(row0 + r) * N + col] = (bf16)v;
        }
      }
    }
  }
}

// ---------------------------------------------------------------- attention
// One block = (b, h, 32 q-rows). qkv ld = 1536 (Q cols 0..767, K cols 768..1535).
__global__ void __launch_bounds__(256) attn_kernel(const bf16* __restrict__ qkv,
    const bf16* __restrict__ vt, const float* __restrict__ p, const float* __restrict__ s,
    const int* __restrict__ mask, const float* __restrict__ compat,
    const float* __restrict__ gamma, int l, bf16* __restrict__ ctx) {
  __shared__ float scb[32 * 512];  // 64 KB
  const int tid = threadIdx.x;
  const int lane = tid & 63;
  const int w = tid >> 6;
  const int fr = lane & 15, fq = lane >> 4;
  const int qc = blockIdx.x, h = blockIdx.y, b = blockIdx.z;
  const int i0 = qc * 32;
  const float* Cm = compat + (size_t)(l * 12 + h) * 4;  // 2x2 row-major [k][j]
  const float gl = gamma[l];

  // ---- phase 1: scores
  bf16x8 qf[2][2];
  #pragma unroll
  for (int mt = 0; mt < 2; mt++)
    #pragma unroll
    for (int kk = 0; kk < 2; kk++)
      qf[mt][kk] = *(const bf16x8*)&qkv[(size_t)(b * 512 + i0 + mt * 16 + fr) * 1536 + h * 64 + kk * 32 + fq * 8];
  for (int ntl = 0; ntl < 8; ++ntl) {
    int j0 = (w * 8 + ntl) * 16;
    bf16x8 kf0 = *(const bf16x8*)&qkv[(size_t)(b * 512 + j0 + fr) * 1536 + 768 + h * 64 + fq * 8];
    bf16x8 kf1 = *(const bf16x8*)&qkv[(size_t)(b * 512 + j0 + fr) * 1536 + 768 + h * 64 + 32 + fq * 8];
    #pragma unroll
    for (int mt = 0; mt < 2; mt++) {
      f32x4 acc = {};
      acc = __builtin_amdgcn_mfma_f32_16x16x32_bf16(qf[mt][0], kf0, acc, 0, 0, 0);
      acc = __builtin_amdgcn_mfma_f32_16x16x32_bf16(qf[mt][1], kf1, acc, 0, 0, 0);
      #pragma unroll
      for (int r = 0; r < 4; r++)
        scb[(mt * 16 + fq * 4 + r) * 512 + j0 + fr] = acc[r] * 0.125f;
    }
  }
  __syncthreads();

  // ---- phase 2: bias + softmax (8 rows per wave, 8 cols per lane, stride 64)
  for (int il = 0; il < 8; ++il) {
    int i = w * 8 + il;
    int qi = i0 + i;
    float p0 = p[(b * 512 + qi) * 2], p1 = p[(b * 512 + qi) * 2 + 1];
    float cp0 = p0 * Cm[0] + p1 * Cm[2];
    float cp1 = p0 * Cm[1] + p1 * Cm[3];
    float x[8]; float mx = -3.0e38f;
    #pragma unroll
    for (int jj = 0; jj < 8; jj++) {
      int j = lane + jj * 64;
      float pj0 = p[(b * 512 + j) * 2], pj1 = p[(b * 512 + j) * 2 + 1];
      float add = (1.f - (float)mask[b * 512 + j]) * -10000.f;
      float v = scb[i * 512 + j] + cp0 * pj0 + cp1 * pj1 + gl * s[b * 512 + j] + add;
      x[jj] = v; mx = fmaxf(mx, v);
    }
    #pragma unroll
    for (int off = 32; off; off >>= 1) mx = fmaxf(mx, __shfl_xor(mx, off));
    float sum = 0.f;
    #pragma unroll
    for (int jj = 0; jj < 8; jj++) { float e = __expf(x[jj] - mx); x[jj] = e; sum += e; }
    #pragma unroll
    for (int off = 32; off; off >>= 1) sum += __shfl_xor(sum, off);
    float inv = 1.f / sum;
    #pragma unroll
    for (int jj = 0; jj < 8; jj++) scb[i * 512 + lane + jj * 64] = x[jj] * inv;
  }
  __syncthreads();

  // ---- phase 3: ctx = P V
  const int mt = w & 1;
  const int ntb = (w >> 1) * 2;
  f32x4 acc[2] = {};
  for (int kt = 0; kt < 16; ++kt) {
    bf16x8 af;
    const float* prow = &scb[(mt * 16 + fr) * 512 + kt * 32 + fq * 8];
    #pragma unroll
    for (int jj = 0; jj < 8; jj++) af[jj] = (bf16)prow[jj];
    #pragma unroll
    for (int np = 0; np < 2; np++) {
      bf16x8 vf = *(const bf16x8*)&vt[(size_t)((b * 12 + h) * 64 + (ntb + np) * 16 + fr) * 512 + kt * 32 + fq * 8];
      acc[np] = __builtin_amdgcn_mfma_f32_16x16x32_bf16(af, vf, acc[np], 0, 0, 0);
    }
  }
  #pragma unroll
  for (int np = 0; np < 2; np++)
    #pragma unroll
    for (int r = 0; r < 4; r++)
      ctx[(size_t)(b * 512 + i0 + mt * 16 + fq * 4 + r) * 768 + h * 64 + (ntb + np) * 16 + fr] = (bf16)acc[np][r];
}

// ---------------------------------------------------------------- launcher
extern "C" void kernel_launch(void* const* d_in, const int* in_sizes, int n_in,
                              void* d_out, int out_size, void* d_ws, size_t ws_size,
                              hipStream_t stream) {
  const int*   input_ids  = (const int*)d_in[0];
  const int*   attn_mask  = (const int*)d_in[1];
  const float* tok_emb    = (const float*)d_in[2];
  const float* pos_emb    = (const float*)d_in[3];
  const float* lang_emb   = (const float*)d_in[4];
  const float* switch_emb = (const float*)d_in[5];
  const float* prototypes = (const float*)d_in[6];
  const float* log_tau    = (const float*)d_in[7];
  const float* emb_ln_w   = (const float*)d_in[8];
  const float* emb_ln_b   = (const float*)d_in[9];
  const float* Wq   = (const float*)d_in[10];
  const float* Wk   = (const float*)d_in[11];
  const float* Wv   = (const float*)d_in[12];
  const float* Wo   = (const float*)d_in[13];
  const float* Wo_b = (const float*)d_in[14];
  const float* compat = (const float*)d_in[15];
  const float* gamma  = (const float*)d_in[16];
  const float* W1   = (const float*)d_in[17];
  const float* b1   = (const float*)d_in[18];
  const float* W2   = (const float*)d_in[19];
  const float* b2   = (const float*)d_in[20];
  const float* ln1_w = (const float*)d_in[21];
  const float* ln1_b = (const float*)d_in[22];
  const float* ln2_w = (const float*)d_in[23];
  const float* ln2_b = (const float*)d_in[24];

  char* wsp = (char*)d_ws;
  size_t off = 0;
  auto alloc = [&](size_t bytes) { void* pp = wsp + off; off += (bytes + 255) & ~(size_t)255; return pp; };
  float* h_f      = (float*)alloc(MN_SZ * 4);
  bf16*  h_bf     = (bf16*)alloc(MN_SZ * 2);
  float* h_base   = (float*)alloc(MN_SZ * 4);
  float* h_mid    = (float*)alloc(MN_SZ * 4);
  bf16*  h_mid_bf = (bf16*)alloc(MN_SZ * 2);
  float* tmp      = (float*)alloc(MN_SZ * 4 * 2);  // split-K partials z=0,1
  float* p_buf    = (float*)alloc((size_t)N_TOK * 2 * 4);
  float* s_buf    = (float*)alloc((size_t)N_TOK * 4);
  bf16*  qkv      = (bf16*)alloc((size_t)N_TOK * 1536 * 2);
  bf16*  vt       = (bf16*)alloc(MN_SZ * 2);
  bf16*  ctx      = (bf16*)alloc(MN_SZ * 2);
  bf16*  a1       = (bf16*)alloc((size_t)N_TOK * F_SZ * 2);
  bf16*  wqkv_bf  = (bf16*)alloc((size_t)L_SZ * 2304 * 768 * 2);
  bf16*  wo_bf    = (bf16*)alloc((size_t)L_SZ * 768 * 768 * 2);
  bf16*  w1_bf    = (bf16*)alloc((size_t)L_SZ * 3072 * 768 * 2);
  bf16*  w2_bf    = (bf16*)alloc((size_t)L_SZ * 768 * 3072 * 2);
  (void)ws_size; (void)in_sizes; (void)n_in; (void)out_size;

  // weight conversion (every call; inputs restored each timed iteration)
  build_wqkv_kernel<<<(12 * 2304 * 768 / 4 + 255) / 256, 256, 0, stream>>>(Wq, Wk, Wv, wqkv_bf);
  f2b_kernel<<<(12 * 768 * 768 / 4 + 255) / 256, 256, 0, stream>>>(Wo, wo_bf, 12 * 768 * 768 / 4);
  f2b_kernel<<<(12 * 3072 * 768 / 4 + 255) / 256, 256, 0, stream>>>(W1, w1_bf, 12 * 3072 * 768 / 4);
  f2b_kernel<<<(12 * 768 * 3072 / 4 + 255) / 256, 256, 0, stream>>>(W2, w2_bf, 12 * 768 * 3072 / 4);

  // embedding stage
  embed_a_kernel<<<N_TOK, 256, 0, stream>>>(input_ids, tok_emb, pos_emb, prototypes, log_tau,
                                            h_base, p_buf);
  embed_c_kernel<<<N_TOK, 256, 0, stream>>>(h_base, p_buf, lang_emb, switch_emb, emb_ln_w,
                                            emb_ln_b, s_buf, h_f, h_bf);

  for (int l = 0; l < 12; ++l) {
    gemm_nt<3><<<dim3(32, 18), 256, 0, stream>>>(h_bf, wqkv_bf + (size_t)l * 2304 * 768, qkv,
                                                 vt, nullptr, N_TOK, 2304, 768);
    attn_kernel<<<dim3(16, 12, 8), 256, 0, stream>>>(qkv, vt, p_buf, s_buf, attn_mask,
                                                     compat, gamma, l, ctx);
    gemm_nt<1><<<dim3(32, 6, 2), 256, 0, stream>>>(ctx, wo_bf + (size_t)l * 768 * 768, tmp,
                                                   nullptr, nullptr, N_TOK, 768, 768);
    ln3_kernel<<<N_TOK, 256, 0, stream>>>(h_f, tmp, tmp + MN_SZ, Wo_b + l * 768,
                                          ln1_w + l * 768, ln1_b + l * 768, h_mid, h_mid_bf);
    gemm_nt<2><<<dim3(32, 24), 256, 0, stream>>>(h_mid_bf, w1_bf + (size_t)l * 3072 * 768, a1,
                                                 nullptr, b1 + l * 3072, N_TOK, 3072, 768);
    gemm_nt<1><<<dim3(32, 6, 2), 256, 0, stream>>>(a1, w2_bf + (size_t)l * 768 * 3072, tmp,
                                                   nullptr, nullptr, N_TOK, 768, 3072);
    float* hdst = (l == 11) ? (float*)d_out : h_f;
    ln3_kernel<<<N_TOK, 256, 0, stream>>>(h_mid, tmp, tmp + MN_SZ, b2 + l * 768,
                                          ln2_w + l * 768, ln2_b + l * 768, hdst, h_bf);
  }
}

// Round 3
// 2868.294 us; speedup vs baseline: 1.2796x; 1.0817x over previous
//
#include <hip/hip_runtime.h>
#include <hip/hip_bf16.h>
#include <math.h>

// SBERTa forward, MI355X gfx950.
// B=8 T=512 D=768 L=12 H=12 F=3072 K=2 DH=64, N_tok=4096.
// GEMMs: bf16 MFMA 16x16x32, NT layout, 128x128x32 tile, 4 waves, m97-style
// global_load_lds width-16 staging. Wo/W2 split-K=4 (768 blocks = 3/CU).
// Attention: padded score LDS (pitch 516), softmax held in regs, P stored bf16
// in reused LDS, phase-3 fragments via ds_read_b128.

typedef __bf16 bf16;
typedef __attribute__((ext_vector_type(8))) __bf16 bf16x8;
typedef __attribute__((ext_vector_type(4))) __bf16 bf16x4;
typedef __attribute__((ext_vector_type(4))) float f32x4;

#define N_TOK 4096
#define D_SZ 768
#define F_SZ 3072
#define L_SZ 12
#define MN_SZ ((size_t)N_TOK * D_SZ)
#define SPITCH 516  // f32 score pitch (pad 4 -> 2-way bank alias only, free)
#define PPITCH 520  // bf16 P pitch (spreads ds_read_b128 across bank groups)

// async global->LDS, 16B per lane, wave-uniform LDS base + lane*16
__device__ __forceinline__ void async_ld16(const void* g, void* l) {
  __builtin_amdgcn_global_load_lds((const __attribute__((address_space(1))) void*)g,
                                   (__attribute__((address_space(3))) void*)l, 16, 0, 0);
}

// ---------------------------------------------------------------- reductions
__device__ inline void block_reduce2(float& a, float& b, int tid) {
  #pragma unroll
  for (int off = 32; off; off >>= 1) {
    a += __shfl_xor(a, off);
    b += __shfl_xor(b, off);
  }
  __shared__ float red[8];
  if ((tid & 63) == 0) { red[tid >> 6] = a; red[4 + (tid >> 6)] = b; }
  __syncthreads();
  a = red[0] + red[1] + red[2] + red[3];
  b = red[4] + red[5] + red[6] + red[7];
  __syncthreads();
}

// ---------------------------------------------------------------- converts
__global__ void __launch_bounds__(256) f2b_kernel(const float* __restrict__ src,
                                                  bf16* __restrict__ dst, int n4) {
  int i = blockIdx.x * 256 + threadIdx.x;
  if (i >= n4) return;
  float4 v = ((const float4*)src)[i];
  bf16x4 o; o.x = (bf16)v.x; o.y = (bf16)v.y; o.z = (bf16)v.z; o.w = (bf16)v.w;
  *(bf16x4*)(dst + (size_t)i * 4) = o;
}

// wqkv layout: per layer, rows 0..767 = Wq[l], 768..1535 = Wk[l], 1536.. = Wv[l]; ld=768
__global__ void __launch_bounds__(256) build_wqkv_kernel(const float* __restrict__ Wq,
    const float* __restrict__ Wk, const float* __restrict__ Wv, bf16* __restrict__ dst) {
  int i = blockIdx.x * 256 + threadIdx.x;
  const int per_layer = 2304 * 768;
  long idx = (long)i * 4;
  if (idx >= 12L * per_layer) return;
  int l = (int)(idx / per_layer);
  int rem = (int)(idx - (long)l * per_layer);
  int r = rem / 768;
  int c = rem - r * 768;
  const float* src;
  if (r < 768)       src = Wq + ((size_t)l * 768 + r) * 768 + c;
  else if (r < 1536) src = Wk + ((size_t)l * 768 + (r - 768)) * 768 + c;
  else               src = Wv + ((size_t)l * 768 + (r - 1536)) * 768 + c;
  float4 v = *(const float4*)src;
  bf16x4 o; o.x = (bf16)v.x; o.y = (bf16)v.y; o.z = (bf16)v.z; o.w = (bf16)v.w;
  *(bf16x4*)(dst + idx) = o;
}

// ---------------------------------------------------------------- embedding
__global__ void __launch_bounds__(256) embed_a_kernel(const int* __restrict__ ids,
    const float* __restrict__ tok, const float* __restrict__ pos,
    const float* __restrict__ proto, const float* __restrict__ log_tau,
    float* __restrict__ h_base, float* __restrict__ p_out) {
  int n = blockIdx.x;
  int t = n & 511;
  int tid = threadIdx.x;
  int id = ids[n];
  float d0 = 0.f, d1 = 0.f;
  #pragma unroll
  for (int jj = 0; jj < 3; jj++) {
    int j = tid + jj * 256;
    float v = tok[(size_t)id * 768 + j] + pos[(size_t)t * 768 + j];
    h_base[(size_t)n * 768 + j] = v;
    d0 += v * proto[j];
    d1 += v * proto[768 + j];
  }
  block_reduce2(d0, d1, tid);
  if (tid == 0) {
    float tau = fmaxf(__expf(log_tau[0]), 0.25f);
    float a = d0 / tau, bb = d1 / tau;
    float m = fmaxf(a, bb);
    float e0 = __expf(a - m), e1 = __expf(bb - m);
    float si = e0 + e1;
    p_out[n * 2] = e0 / si;
    p_out[n * 2 + 1] = e1 / si;
  }
}

__global__ void __launch_bounds__(256) embed_c_kernel(const float* __restrict__ h_base,
    const float* __restrict__ p, const float* __restrict__ lang, const float* __restrict__ sw,
    const float* __restrict__ lw, const float* __restrict__ lb,
    float* __restrict__ s_out, float* __restrict__ h_out, bf16* __restrict__ h_bf) {
  int n = blockIdx.x;
  int t = n & 511;
  int tid = threadIdx.x;
  float p0 = p[n * 2], p1 = p[n * 2 + 1];
  float sv = 0.f;
  if (t > 0) sv = 1.f - (p0 * p[(n - 1) * 2] + p1 * p[(n - 1) * 2 + 1]);
  if (tid == 0) s_out[n] = sv;
  float x[3]; float sum = 0.f, sq = 0.f;
  #pragma unroll
  for (int jj = 0; jj < 3; jj++) {
    int j = tid + jj * 256;
    float v = h_base[(size_t)n * 768 + j] + p0 * lang[j] + p1 * lang[768 + j] + sv * sw[j];
    x[jj] = v; sum += v; sq += v * v;
  }
  block_reduce2(sum, sq, tid);
  float mean = sum * (1.f / 768.f);
  float var = fmaxf(sq * (1.f / 768.f) - mean * mean, 0.f);
  float inv = rsqrtf(var + 1e-12f);
  #pragma unroll
  for (int jj = 0; jj < 3; jj++) {
    int j = tid + jj * 256;
    float o = (x[jj] - mean) * inv * lw[j] + lb[j];
    h_out[(size_t)n * 768 + j] = o;
    h_bf[(size_t)n * 768 + j] = (bf16)o;
  }
}

// ---------------------------------------------------------------- fused LN (residual + 4 partials)
// out = LN(x1 + t[0..3] + bias) * w + bv ; writes fp32 + bf16
__global__ void __launch_bounds__(256) ln5_kernel(const float* __restrict__ x1,
    const float* __restrict__ t, const float* __restrict__ bias,
    const float* __restrict__ w, const float* __restrict__ bv,
    float* __restrict__ out_f, bf16* __restrict__ out_b) {
  int n = blockIdx.x;
  int tid = threadIdx.x;
  float x[3]; float sum = 0.f, sq = 0.f;
  #pragma unroll
  for (int jj = 0; jj < 3; jj++) {
    int j = tid + jj * 256;
    size_t o = (size_t)n * 768 + j;
    float v = x1[o] + (t[o] + t[o + MN_SZ]) + (t[o + 2 * MN_SZ] + t[o + 3 * MN_SZ]) + bias[j];
    x[jj] = v; sum += v; sq += v * v;
  }
  block_reduce2(sum, sq, tid);
  float mean = sum * (1.f / 768.f);
  float var = fmaxf(sq * (1.f / 768.f) - mean * mean, 0.f);
  float inv = rsqrtf(var + 1e-12f);
  #pragma unroll
  for (int jj = 0; jj < 3; jj++) {
    int j = tid + jj * 256;
    float o = (x[jj] - mean) * inv * w[j] + bv[j];
    out_f[(size_t)n * 768 + j] = o;
    out_b[(size_t)n * 768 + j] = (bf16)o;
  }
}

// ---------------------------------------------------------------- GEMM (NT)
// C[m,n] = sum_k A[m,k]*B[n,k].
// MODE 1: f32 out, split-K over blockIdx.z (gridDim.z pieces), out C + z*M*N.
// MODE 2: bias+gelu, bf16 out.
// MODE 3: QKV: cols <1536 -> bf16 C (ld 1536); cols >=1536 -> transposed into vt C2.
template <int MODE>
__global__ void __launch_bounds__(256) gemm_nt(const bf16* __restrict__ A,
    const bf16* __restrict__ B, void* __restrict__ C, bf16* __restrict__ C2,
    const float* __restrict__ bias, int M, int N, int K) {
  __shared__ bf16 As[128 * 32];
  __shared__ bf16 Bs[128 * 32];
  const int tid = threadIdx.x;
  const int lane = tid & 63;
  const int wave = tid >> 6;
  const int wm = wave >> 1, wn = wave & 1;
  const int m0 = blockIdx.x * 128, n0 = blockIdx.y * 128;
  const int fr = lane & 15, fq = lane >> 4;
  const int srow = wave * 16 + (lane >> 2);
  const int scol = (lane & 3) * 8;

  int kb = 0, ke = K;
  if (MODE == 1) { int ks = K / gridDim.z; kb = blockIdx.z * ks; ke = kb + ks; }

  f32x4 acc[4][4] = {};
  const bf16* Ap = A + (size_t)(m0 + srow) * K + scol;
  const bf16* Bp = B + (size_t)(n0 + srow) * K + scol;
  bf16* AsW = &As[wave * 512];
  bf16* BsW = &Bs[wave * 512];
  for (int k0 = kb; k0 < ke; k0 += 32) {
    async_ld16(Ap + k0, AsW);
    async_ld16(Ap + (size_t)64 * K + k0, AsW + 64 * 32);
    async_ld16(Bp + k0, BsW);
    async_ld16(Bp + (size_t)64 * K + k0, BsW + 64 * 32);
    __syncthreads();
    bf16x8 af[4], bfr[4];
    #pragma unroll
    for (int i = 0; i < 4; i++) af[i]  = *(const bf16x8*)&As[(wm * 64 + i * 16 + fr) * 32 + fq * 8];
    #pragma unroll
    for (int i = 0; i < 4; i++) bfr[i] = *(const bf16x8*)&Bs[(wn * 64 + i * 16 + fr) * 32 + fq * 8];
    #pragma unroll
    for (int i = 0; i < 4; i++)
      #pragma unroll
      for (int j = 0; j < 4; j++)
        acc[i][j] = __builtin_amdgcn_mfma_f32_16x16x32_bf16(af[i], bfr[j], acc[i][j], 0, 0, 0);
    __syncthreads();
  }

  const bool vregion = (MODE == 3) && (n0 >= 1536);
  float* Cz = (MODE == 1) ? ((float*)C + (size_t)blockIdx.z * M * N) : (float*)C;
  #pragma unroll
  for (int i = 0; i < 4; i++) {
    int row0 = m0 + wm * 64 + i * 16 + fq * 4;
    #pragma unroll
    for (int j = 0; j < 4; j++) {
      int col = n0 + wn * 64 + j * 16 + fr;
      if (MODE == 3 && vregion) {
        int vcol = col - 1536;
        int h = vcol >> 6, dh = vcol & 63;
        int b = row0 >> 9, t0 = row0 & 511;
        bf16x4 o;
        #pragma unroll
        for (int r = 0; r < 4; r++) o[r] = (bf16)acc[i][j][r];
        *(bf16x4*)&C2[((size_t)(b * 12 + h) * 64 + dh) * 512 + t0] = o;
      } else {
        #pragma unroll
        for (int r = 0; r < 4; r++) {
          float v = acc[i][j][r];
          if (MODE == 2) {
            v += bias[col];
            v = 0.5f * v * (1.f + erff(v * 0.70710678118654752f));
          }
          if (MODE == 1)      Cz[(size_t)(row0 + r) * N + col] = v;
          else if (MODE == 3) ((bf16*)C)[(size_t)(row0 + r) * 1536 + col] = (bf16)v;
          else                ((bf16*)C)[(size_t)(row0 + r) * N + col] = (bf16)v;
        }
      }
    }
  }
}

// ---------------------------------------------------------------- attention
// One block = (b, h, 32 q-rows). qkv ld = 1536 (Q cols 0..767, K cols 768..1535).
__global__ void __launch_bounds__(256) attn_kernel(const bf16* __restrict__ qkv,
    const bf16* __restrict__ vt, const float* __restrict__ p, const float* __restrict__ s,
    const int* __restrict__ mask, const float* __restrict__ compat,
    const float* __restrict__ gamma, int l, bf16* __restrict__ ctx) {
  __shared__ float scb[32 * SPITCH];  // 66048 B; reused as bf16[32*PPITCH] after softmax
  const int tid = threadIdx.x;
  const int lane = tid & 63;
  const int w = tid >> 6;
  const int fr = lane & 15, fq = lane >> 4;
  const int qc = blockIdx.x, h = blockIdx.y, b = blockIdx.z;
  const int i0 = qc * 32;
  const float* Cm = compat + (size_t)(l * 12 + h) * 4;  // 2x2 row-major [k][j]
  const float gl = gamma[l];

  // ---- phase 1: scores -> scb (fp32, pitch 516: fq aliasing is free 2-way)
  bf16x8 qf[2][2];
  #pragma unroll
  for (int mt = 0; mt < 2; mt++)
    #pragma unroll
    for (int kk = 0; kk < 2; kk++)
      qf[mt][kk] = *(const bf16x8*)&qkv[(size_t)(b * 512 + i0 + mt * 16 + fr) * 1536 + h * 64 + kk * 32 + fq * 8];
  for (int ntl = 0; ntl < 8; ++ntl) {
    int j0 = (w * 8 + ntl) * 16;
    bf16x8 kf0 = *(const bf16x8*)&qkv[(size_t)(b * 512 + j0 + fr) * 1536 + 768 + h * 64 + fq * 8];
    bf16x8 kf1 = *(const bf16x8*)&qkv[(size_t)(b * 512 + j0 + fr) * 1536 + 768 + h * 64 + 32 + fq * 8];
    #pragma unroll
    for (int mt = 0; mt < 2; mt++) {
      f32x4 acc = {};
      acc = __builtin_amdgcn_mfma_f32_16x16x32_bf16(qf[mt][0], kf0, acc, 0, 0, 0);
      acc = __builtin_amdgcn_mfma_f32_16x16x32_bf16(qf[mt][1], kf1, acc, 0, 0, 0);
      #pragma unroll
      for (int r = 0; r < 4; r++)
        scb[(mt * 16 + fq * 4 + r) * SPITCH + j0 + fr] = acc[r] * 0.125f;
    }
  }

  // per-lane column-bias cache (cols j = lane + jj*64), loaded once
  float pj0[8], pj1[8], basej[8];
  #pragma unroll
  for (int jj = 0; jj < 8; jj++) {
    int j = lane + jj * 64;
    pj0[jj] = p[(b * 512 + j) * 2];
    pj1[jj] = p[(b * 512 + j) * 2 + 1];
    basej[jj] = gl * s[b * 512 + j] + (1.f - (float)mask[b * 512 + j]) * -10000.f;
  }
  __syncthreads();

  // ---- phase 2: softmax rows held in registers (8 rows/wave, 8 cols/lane)
  float xs[8][8];
  #pragma unroll
  for (int il = 0; il < 8; ++il) {
    int i = w * 8 + il;
    int qi = i0 + i;
    float p0 = p[(b * 512 + qi) * 2], p1 = p[(b * 512 + qi) * 2 + 1];
    float cp0 = p0 * Cm[0] + p1 * Cm[2];
    float cp1 = p0 * Cm[1] + p1 * Cm[3];
    float mx = -3.0e38f;
    #pragma unroll
    for (int jj = 0; jj < 8; jj++) {
      float v = scb[i * SPITCH + lane + jj * 64] + cp0 * pj0[jj] + cp1 * pj1[jj] + basej[jj];
      xs[il][jj] = v; mx = fmaxf(mx, v);
    }
    #pragma unroll
    for (int off = 32; off; off >>= 1) mx = fmaxf(mx, __shfl_xor(mx, off));
    float sum = 0.f;
    #pragma unroll
    for (int jj = 0; jj < 8; jj++) { float e = __expf(xs[il][jj] - mx); xs[il][jj] = e; sum += e; }
    #pragma unroll
    for (int off = 32; off; off >>= 1) sum += __shfl_xor(sum, off);
    float inv = 1.f / sum;
    #pragma unroll
    for (int jj = 0; jj < 8; jj++) xs[il][jj] *= inv;
  }
  __syncthreads();  // all reads of scb(f32) done -> safe to overwrite as bf16

  bf16* pbf = (bf16*)scb;
  #pragma unroll
  for (int il = 0; il < 8; ++il)
    #pragma unroll
    for (int jj = 0; jj < 8; jj++)
      pbf[(w * 8 + il) * PPITCH + lane + jj * 64] = (bf16)xs[il][jj];
  __syncthreads();

  // ---- phase 3: ctx = P V, P fragments via ds_read_b128
  const int mt3 = w & 1;
  const int ntb = (w >> 1) * 2;
  f32x4 acc3[2] = {};
  for (int kt = 0; kt < 16; ++kt) {
    bf16x8 af = *(const bf16x8*)&pbf[(mt3 * 16 + fr) * PPITCH + kt * 32 + fq * 8];
    #pragma unroll
    for (int np = 0; np < 2; np++) {
      bf16x8 vf = *(const bf16x8*)&vt[(size_t)((b * 12 + h) * 64 + (ntb + np) * 16 + fr) * 512 + kt * 32 + fq * 8];
      acc3[np] = __builtin_amdgcn_mfma_f32_16x16x32_bf16(af, vf, acc3[np], 0, 0, 0);
    }
  }
  #pragma unroll
  for (int np = 0; np < 2; np++)
    #pragma unroll
    for (int r = 0; r < 4; r++)
      ctx[(size_t)(b * 512 + i0 + mt3 * 16 + fq * 4 + r) * 768 + h * 64 + (ntb + np) * 16 + fr] = (bf16)acc3[np][r];
}

// ---------------------------------------------------------------- launcher
extern "C" void kernel_launch(void* const* d_in, const int* in_sizes, int n_in,
                              void* d_out, int out_size, void* d_ws, size_t ws_size,
                              hipStream_t stream) {
  const int*   input_ids  = (const int*)d_in[0];
  const int*   attn_mask  = (const int*)d_in[1];
  const float* tok_emb    = (const float*)d_in[2];
  const float* pos_emb    = (const float*)d_in[3];
  const float* lang_emb   = (const float*)d_in[4];
  const float* switch_emb = (const float*)d_in[5];
  const float* prototypes = (const float*)d_in[6];
  const float* log_tau    = (const float*)d_in[7];
  const float* emb_ln_w   = (const float*)d_in[8];
  const float* emb_ln_b   = (const float*)d_in[9];
  const float* Wq   = (const float*)d_in[10];
  const float* Wk   = (const float*)d_in[11];
  const float* Wv   = (const float*)d_in[12];
  const float* Wo   = (const float*)d_in[13];
  const float* Wo_b = (const float*)d_in[14];
  const float* compat = (const float*)d_in[15];
  const float* gamma  = (const float*)d_in[16];
  const float* W1   = (const float*)d_in[17];
  const float* b1   = (const float*)d_in[18];
  const float* W2   = (const float*)d_in[19];
  const float* b2   = (const float*)d_in[20];
  const float* ln1_w = (const float*)d_in[21];
  const float* ln1_b = (const float*)d_in[22];
  const float* ln2_w = (const float*)d_in[23];
  const float* ln2_b = (const float*)d_in[24];

  char* wsp = (char*)d_ws;
  size_t off = 0;
  auto alloc = [&](size_t bytes) { void* pp = wsp + off; off += (bytes + 255) & ~(size_t)255; return pp; };
  float* h_f      = (float*)alloc(MN_SZ * 4);
  bf16*  h_bf     = (bf16*)alloc(MN_SZ * 2);
  float* h_mid    = (float*)alloc(MN_SZ * 4);
  bf16*  h_mid_bf = (bf16*)alloc(MN_SZ * 2);
  float* tmp      = (float*)alloc(MN_SZ * 4 * 4);   // split-K partials z=0..3
  float* h_base   = tmp + 3 * MN_SZ;                // dead after embedding; overlay
  float* p_buf    = (float*)alloc((size_t)N_TOK * 2 * 4);
  float* s_buf    = (float*)alloc((size_t)N_TOK * 4);
  bf16*  qkv      = (bf16*)alloc((size_t)N_TOK * 1536 * 2);
  bf16*  vt       = (bf16*)alloc(MN_SZ * 2);
  bf16*  ctx      = (bf16*)alloc(MN_SZ * 2);
  bf16*  a1       = (bf16*)alloc((size_t)N_TOK * F_SZ * 2);
  bf16*  wqkv_bf  = (bf16*)alloc((size_t)L_SZ * 2304 * 768 * 2);
  bf16*  wo_bf    = (bf16*)alloc((size_t)L_SZ * 768 * 768 * 2);
  bf16*  w1_bf    = (bf16*)alloc((size_t)L_SZ * 3072 * 768 * 2);
  bf16*  w2_bf    = (bf16*)alloc((size_t)L_SZ * 768 * 3072 * 2);
  (void)ws_size; (void)in_sizes; (void)n_in; (void)out_size;

  // weight conversion (every call; inputs restored each timed iteration)
  build_wqkv_kernel<<<(12 * 2304 * 768 / 4 + 255) / 256, 256, 0, stream>>>(Wq, Wk, Wv, wqkv_bf);
  f2b_kernel<<<(12 * 768 * 768 / 4 + 255) / 256, 256, 0, stream>>>(Wo, wo_bf, 12 * 768 * 768 / 4);
  f2b_kernel<<<(12 * 3072 * 768 / 4 + 255) / 256, 256, 0, stream>>>(W1, w1_bf, 12 * 3072 * 768 / 4);
  f2b_kernel<<<(12 * 768 * 3072 / 4 + 255) / 256, 256, 0, stream>>>(W2, w2_bf, 12 * 768 * 3072 / 4);

  // embedding stage
  embed_a_kernel<<<N_TOK, 256, 0, stream>>>(input_ids, tok_emb, pos_emb, prototypes, log_tau,
                                            h_base, p_buf);
  embed_c_kernel<<<N_TOK, 256, 0, stream>>>(h_base, p_buf, lang_emb, switch_emb, emb_ln_w,
                                            emb_ln_b, s_buf, h_f, h_bf);

  for (int l = 0; l < 12; ++l) {
    gemm_nt<3><<<dim3(32, 18), 256, 0, stream>>>(h_bf, wqkv_bf + (size_t)l * 2304 * 768, qkv,
                                                 vt, nullptr, N_TOK, 2304, 768);
    attn_kernel<<<dim3(16, 12, 8), 256, 0, stream>>>(qkv, vt, p_buf, s_buf, attn_mask,
                                                     compat, gamma, l, ctx);
    gemm_nt<1><<<dim3(32, 6, 4), 256, 0, stream>>>(ctx, wo_bf + (size_t)l * 768 * 768, tmp,
                                                   nullptr, nullptr, N_TOK, 768, 768);
    ln5_kernel<<<N_TOK, 256, 0, stream>>>(h_f, tmp, Wo_b + l * 768,
                                          ln1_w + l * 768, ln1_b + l * 768, h_mid, h_mid_bf);
    gemm_nt<2><<<dim3(32, 24), 256, 0, stream>>>(h_mid_bf, w1_bf + (size_t)l * 3072 * 768, a1,
                                                 nullptr, b1 + l * 3072, N_TOK, 3072, 768);
    gemm_nt<1><<<dim3(32, 6, 4), 256, 0, stream>>>(a1, w2_bf + (size_t)l * 768 * 3072, tmp,
                                                   nullptr, nullptr, N_TOK, 768, 3072);
    float* hdst = (l == 11) ? (float*)d_out : h_f;
    ln5_kernel<<<N_TOK, 256, 0, stream>>>(h_mid, tmp, b2 + l * 768,
                                          ln2_w + l * 768, ln2_b + l * 768, hdst, h_bf);
  }
}